// Round 4
// baseline (281.436 us; speedup 1.0000x reference)
//
#include <hip/hip_runtime.h>
#include <math.h>
#include <stdint.h>

#define TOKENS 8192
#define DIM 1024
#define N3 3072
#define NSEQ 2048
#define NH 16
#define DH 64

typedef __attribute__((ext_vector_type(8))) __bf16 bf16x8;
typedef __attribute__((ext_vector_type(4))) float f32x4;
typedef __attribute__((ext_vector_type(16))) float f32x16;
typedef __attribute__((ext_vector_type(4))) short short4v;

// hardware bf16 convert (RNE) — no builtin on gfx950, inline asm per T12/m240
__device__ __forceinline__ unsigned cvt2bf(float a, float b) {
    unsigned r;
    asm("v_cvt_pk_bf16_f32 %0, %1, %2" : "=v"(r) : "v"(a), "v"(b));
    return r;
}
__device__ __forceinline__ unsigned short f2bf(float f) {
    unsigned r;
    asm("v_cvt_pk_bf16_f32 %0, %1, %1" : "=v"(r) : "v"(f));
    return (unsigned short)r;
}

__device__ __forceinline__ void glds16(const void* g, void* l) {
    __builtin_amdgcn_global_load_lds((__attribute__((address_space(1))) void*)(void*)g,
                                     (__attribute__((address_space(3))) void*)l, 16, 0, 0);
}

// ---------------- transpose f32 [R][C] -> bf16 [C][R] ----------------
__global__ __launch_bounds__(256) void transpose_to_bf16(
    const float* __restrict__ in, unsigned short* __restrict__ out, int R, int C) {
    __shared__ float tile[64][65];
    int n0 = blockIdx.x * 64, k0 = blockIdx.y * 64;
    int t = threadIdx.x;
#pragma unroll
    for (int i = 0; i < 16; i++) {
        int idx = i * 256 + t;
        int r = idx >> 6, c = idx & 63;
        tile[r][c] = in[(size_t)(k0 + r) * C + n0 + c];
    }
    __syncthreads();
#pragma unroll
    for (int i = 0; i < 16; i++) {
        int idx = i * 256 + t;
        int r = idx >> 6, c = idx & 63;
        out[(size_t)(n0 + r) * R + k0 + c] = f2bf(tile[c][r]);
    }
}

// ---------------- LayerNorm: f32 [8192][1024] -> bf16 ----------------
__global__ __launch_bounds__(256) void ln_kernel(
    const float* __restrict__ x, const float* __restrict__ gamma,
    const float* __restrict__ beta, unsigned short* __restrict__ xn) {
    int row = blockIdx.x;
    int t = threadIdx.x;
    const float4 v = ((const float4*)(x + (size_t)row * DIM))[t];
    float s = v.x + v.y + v.z + v.w;
    float sq = v.x * v.x + v.y * v.y + v.z * v.z + v.w * v.w;
#pragma unroll
    for (int m = 1; m < 64; m <<= 1) {
        s += __shfl_xor(s, m);
        sq += __shfl_xor(sq, m);
    }
    __shared__ float ws[4], wq[4];
    int w = t >> 6, lane = t & 63;
    if (lane == 0) { ws[w] = s; wq[w] = sq; }
    __syncthreads();
    s = ws[0] + ws[1] + ws[2] + ws[3];
    sq = wq[0] + wq[1] + wq[2] + wq[3];
    float mu = s * (1.0f / DIM);
    float var = sq * (1.0f / DIM) - mu * mu;
    float rstd = rsqrtf(var + 1e-5f);
    const float4 g = ((const float4*)gamma)[t];
    const float4 bb = ((const float4*)beta)[t];
    uint2 o;
    o.x = cvt2bf((v.x - mu) * rstd * g.x + bb.x, (v.y - mu) * rstd * g.y + bb.y);
    o.y = cvt2bf((v.z - mu) * rstd * g.z + bb.z, (v.w - mu) * rstd * g.w + bb.w);
    *(uint2*)(xn + (size_t)row * DIM + t * 4) = o;
}

// XCD-aware bijective swizzle of the linear workgroup id (nwg % 8 == 0)
__device__ __forceinline__ void xcd_swizzle(int& bx, int& by) {
    int nwgx = gridDim.x;
    int nwg = nwgx * gridDim.y;
    int wg = by * nwgx + bx;
    int cpx = nwg >> 3;
    int swz = (wg & 7) * cpx + (wg >> 3);
    bx = swz % nwgx;
    by = swz / nwgx;
}

// ---------------- shared GEMM core: C[128x128] = A[M,K] * Bt[N,K]^T ----------------
__device__ __forceinline__ void gemm_core(
    const unsigned short* __restrict__ A, const unsigned short* __restrict__ Bt, int K,
    int brow, int bcol, short* As, short* Bs, f32x4 acc[4][4]) {
    int t = threadIdx.x, w = t >> 6, lane = t & 63;
    int wr = w >> 1, wc = w & 1;
    int srow = lane >> 2, scol = (lane & 3) * 8;
    for (int k0 = 0; k0 < K; k0 += 32) {
        __syncthreads();
#pragma unroll
        for (int i = 0; i < 2; i++) {
            int c = i * 4 + w;
            glds16(A + (size_t)(brow + 16 * c + srow) * K + k0 + scol, (char*)As + c * 1024);
            glds16(Bt + (size_t)(bcol + 16 * c + srow) * K + k0 + scol, (char*)Bs + c * 1024);
        }
        __syncthreads();
        bf16x8 a[4], b[4];
#pragma unroll
        for (int i = 0; i < 4; i++) {
            a[i] = *(const bf16x8*)&As[(wr * 64 + i * 16 + (lane & 15)) * 32 + (lane >> 4) * 8];
            b[i] = *(const bf16x8*)&Bs[(wc * 64 + i * 16 + (lane & 15)) * 32 + (lane >> 4) * 8];
        }
#pragma unroll
        for (int i = 0; i < 4; i++)
#pragma unroll
            for (int j = 0; j < 4; j++)
                acc[i][j] = __builtin_amdgcn_mfma_f32_16x16x32_bf16(a[i], b[j], acc[i][j], 0, 0, 0);
    }
}

// QKV GEMM: xn[8192][1024] @ w_qkv -> writes Q (scaled), K, V^T in [b,h,...] layouts
#define QSCALE_LOG2E 0.18033688011112042f  // (1/sqrt(64)) * log2(e)

__global__ __launch_bounds__(256) void gemm_qkv(
    const unsigned short* __restrict__ A, const unsigned short* __restrict__ Bt,
    unsigned short* __restrict__ Qb, unsigned short* __restrict__ Kb,
    unsigned short* __restrict__ Vt) {
    __shared__ __align__(16) short As[128 * 32];
    __shared__ __align__(16) short Bs[128 * 32];
    int bx = blockIdx.x, by = blockIdx.y;
    xcd_swizzle(bx, by);
    int brow = by * 128, bcol = bx * 128;
    f32x4 acc[4][4] = {};
    gemm_core(A, Bt, DIM, brow, bcol, As, Bs, acc);

    int t = threadIdx.x, w = t >> 6, lane = t & 63;
    int wr = w >> 1, wc = w & 1;
    int part = bcol >> 10;  // uniform per block: 0=q 1=k 2=v
#pragma unroll
    for (int i = 0; i < 4; i++) {
#pragma unroll
        for (int j = 0; j < 4; j++) {
            int col = bcol + wc * 64 + j * 16 + (lane & 15);
            int within = col & 1023;
            int h = within >> 6, d = within & 63;
            int rowb = brow + wr * 64 + i * 16 + (lane >> 4) * 4;
            if (part == 2) {
                // V^T: n consecutive over r -> pack 4
                int b = rowb >> 11, n = rowb & 2047;
                int bh = (b << 4) + h;
                uint2 pv;
                pv.x = cvt2bf(acc[i][j][0], acc[i][j][1]);
                pv.y = cvt2bf(acc[i][j][2], acc[i][j][3]);
                *(uint2*)(Vt + ((size_t)bh * 64 + d) * 2048 + n) = pv;
            } else {
#pragma unroll
                for (int r = 0; r < 4; r++) {
                    int row = rowb + r;
                    int b = row >> 11, n = row & 2047;
                    int bh = (b << 4) + h;
                    float val = acc[i][j][r];
                    if (part == 0)
                        Qb[((size_t)bh * 2048 + n) * 64 + d] = f2bf(val * QSCALE_LOG2E);
                    else
                        Kb[((size_t)bh * 2048 + n) * 64 + d] = f2bf(val);
                }
            }
        }
    }
}

// out GEMM: att[8192][1024] @ w_out + b_out -> f32 out
__global__ __launch_bounds__(256) void gemm_out(
    const unsigned short* __restrict__ A, const unsigned short* __restrict__ Bt,
    const float* __restrict__ bias, float* __restrict__ out) {
    __shared__ __align__(16) short As[128 * 32];
    __shared__ __align__(16) short Bs[128 * 32];
    int bx = blockIdx.x, by = blockIdx.y;
    xcd_swizzle(bx, by);
    int brow = by * 128, bcol = bx * 128;
    f32x4 acc[4][4] = {};
    gemm_core(A, Bt, DIM, brow, bcol, As, Bs, acc);

    int t = threadIdx.x, w = t >> 6, lane = t & 63;
    int wr = w >> 1, wc = w & 1;
#pragma unroll
    for (int i = 0; i < 4; i++) {
#pragma unroll
        for (int j = 0; j < 4; j++) {
            int col = bcol + wc * 64 + j * 16 + (lane & 15);
            float bv = bias[col];
#pragma unroll
            for (int r = 0; r < 4; r++) {
                int row = brow + wr * 64 + i * 16 + (lane >> 4) * 4 + r;
                out[(size_t)row * DIM + col] = acc[i][j][r] + bv;
            }
        }
    }
}

// ---------------- flash attention v2: 32x32 MFMA, in-register softmax (T12) ----------------
// grid (16, 64): 1024 blocks, 4 waves/block, QBLK=32 rows/wave (block = 128 q-rows).
// Swapped QK^T: S^T[kv][q] = mfma32(K_frag, Q_frag); lane = q-col (lane&31), holds 32 of
// 64 kv values (partner lane^32 has the other half). Softmax fully in-register; P->B-frag
// via cvt_pk + v_permlane32_swap. K/V LDS staged FRAGMENT-ORDERED (chunk c = frag id,
// lane-linear 16B) -> conflict-free ds_read_b128 and trivial read addressing.
#define LOG2E_THR 11.5f  // defer-max threshold: 8 * log2(e)

__global__ __launch_bounds__(256) void attn_kernel(
    const unsigned short* __restrict__ Qb, const unsigned short* __restrict__ Kb,
    const unsigned short* __restrict__ Vt, const float* __restrict__ pos,
    unsigned short* __restrict__ att) {
    __shared__ __align__(16) char Ks[2][8192];
    __shared__ __align__(16) char Vs[2][8192];
    int t = threadIdx.x, w = t >> 6, lane = t & 63;
    int l31 = lane & 31, lhi = lane >> 5;

    // XCD head-grouping: all q-tiles of head y land on XCD y%8 (8 heads * 512KB KV = 4MB L2)
    int L = blockIdx.y * gridDim.x + blockIdx.x;      // 0..1023
    int bh = (L & 7) + (((L >> 3) & 7) << 3);         // head-batch index 0..63
    int qt = L >> 6;                                  // q-tile 0..15
    int b = bh >> 4, h = bh & 15;
    int qr = qt * 128 + w * 32 + l31;                 // this lane's q row

    const unsigned short* Qh = Qb + (size_t)bh * NSEQ * DH;
    const char* Khc = (const char*)(Kb + (size_t)bh * NSEQ * DH);
    const char* Vhc = (const char*)(Vt + (size_t)bh * DH * NSEQ);

    // Q fragments: qf[ks] = Q[qr][ks*16 + lhi*8 .. +8]  (B-frag k = ks*16 + lhi*8 + j)
    bf16x8 qf[4];
#pragma unroll
    for (int ks = 0; ks < 4; ks++)
        qf[ks] = *(const bf16x8*)(Qh + (size_t)qr * DH + ks * 16 + lhi * 8);

    f32x16 oacc[2] = {};
    float mrun = -INFINITY, lsum = 0.f;  // per-lane partials (pair-combined at epilogue)

    // fragment-ordered cooperative stage: chunk c (0..7) = frag(kt|dt, ks);
    // lane l supplies element (row = *t*32 + (l&31), k-chunk = ks*16 + (l>>5)*8)
    auto stage = [&](int buf, int kv0) {
#pragma unroll
        for (int i2 = 0; i2 < 2; i2++) {
            int c = i2 * 4 + w;
            int ct = c >> 2, cs = c & 3;
            glds16(Khc + (size_t)(kv0 + ct * 32 + l31) * 128 + cs * 32 + lhi * 16,
                   Ks[buf] + c * 1024);
            glds16(Vhc + (size_t)(ct * 32 + l31) * 4096 + (size_t)(kv0 + cs * 16 + lhi * 8) * 2,
                   Vs[buf] + c * 1024);
        }
    };

    stage(0, 0);
    asm volatile("s_waitcnt vmcnt(0)");
    __syncthreads();
    int cur = 0;

    for (int kv0 = 0; kv0 < NSEQ; kv0 += 64) {
        if (kv0 + 64 < NSEQ) stage(cur ^ 1, kv0 + 64);  // prefetch next tile

        const char* Kc = Ks[cur];
        const char* Vc = Vs[cur];

        // QK^T: st[kt] = S^T tile [kv = kv0+kt*32+...][q]; lane col q, rows m(r)+4*lhi
        f32x16 st[2];
        __builtin_amdgcn_s_setprio(1);
#pragma unroll
        for (int kt = 0; kt < 2; kt++) {
            f32x16 s = {};
#pragma unroll
            for (int ks = 0; ks < 4; ks++) {
                bf16x8 kf = *(const bf16x8*)(Kc + (kt * 4 + ks) * 1024 + lane * 16);
                s = __builtin_amdgcn_mfma_f32_32x32x16_bf16(kf, qf[ks], s, 0, 0, 0);
            }
            st[kt] = s;
        }
        __builtin_amdgcn_s_setprio(0);

        // in-lane max over 32 vals + pair combine via permlane32_swap
        float pm = fmaxf(st[0][0], st[0][1]);
#pragma unroll
        for (int kt = 0; kt < 2; kt++)
#pragma unroll
            for (int r = 0; r < 16; r++)
                if (!(kt == 0 && r < 2)) pm = fmaxf(pm, st[kt][r]);
        {
            float pa = pm, pb = pm;
            asm("v_permlane32_swap_b32 %0, %1" : "+v"(pa), "+v"(pb));
            pm = fmaxf(pa, pb);
        }
        if (!__all(pm - mrun <= LOG2E_THR)) {
            float mnew = fmaxf(mrun, pm);
            float scale = exp2f(mrun - mnew);
            lsum *= scale;
            oacc[0] *= scale;
            oacc[1] *= scale;
            mrun = mnew;
        }
        // P = exp2(S - mrun) in place; per-lane partial sum
        float rsum = 0.f;
#pragma unroll
        for (int kt = 0; kt < 2; kt++)
#pragma unroll
            for (int r = 0; r < 16; r++) {
                float e = exp2f(st[kt][r] - mrun);
                st[kt][r] = e;
                rsum += e;
            }
        lsum += rsum;

        // build PV B-frags: per k-step ks, words w0..w3 from own+partner rows.
        // own rows (lane<32): m(r)=(r&3)+8*(r>>2); partner +4. One swap fills two words.
        bf16x8 bfr[4];
#pragma unroll
        for (int ks = 0; ks < 4; ks++) {
            int kt = ks >> 1, rb = (ks & 1) * 8;
            unsigned pa = cvt2bf(st[kt][rb + 0], st[kt][rb + 1]);
            unsigned pc = cvt2bf(st[kt][rb + 2], st[kt][rb + 3]);
            unsigned pb = cvt2bf(st[kt][rb + 4], st[kt][rb + 5]);
            unsigned pd = cvt2bf(st[kt][rb + 6], st[kt][rb + 7]);
            asm("v_permlane32_swap_b32 %0, %1" : "+v"(pa), "+v"(pb));
            asm("v_permlane32_swap_b32 %0, %1" : "+v"(pc), "+v"(pd));
            uint4 pw = {pa, pc, pb, pd};
            bfr[ks] = *(bf16x8*)&pw;
        }

        // PV: oacc[dt] += V^T_frag(dt,ks) * P^T_frag(ks)
        __builtin_amdgcn_s_setprio(1);
#pragma unroll
        for (int ks = 0; ks < 4; ks++)
#pragma unroll
            for (int dt = 0; dt < 2; dt++) {
                bf16x8 vf = *(const bf16x8*)(Vc + (dt * 4 + ks) * 1024 + lane * 16);
                oacc[dt] = __builtin_amdgcn_mfma_f32_32x32x16_bf16(vf, bfr[ks], oacc[dt], 0, 0, 0);
            }
        __builtin_amdgcn_s_setprio(0);

        asm volatile("s_waitcnt vmcnt(0)");  // prefetch landed
        __syncthreads();
        cur ^= 1;
    }

    // epilogue: pair-combine lsum, then out[q][d] = oacc/lsum + pos, bf16
    {
        float pa = lsum, pb = lsum;
        asm("v_permlane32_swap_b32 %0, %1" : "+v"(pa), "+v"(pb));
        lsum = pa + pb;
    }
    float inv = 1.0f / lsum;
    size_t rowbase = ((size_t)b * NSEQ + qr) * DIM + h * 64;
#pragma unroll
    for (int dt = 0; dt < 2; dt++)
#pragma unroll
        for (int g4 = 0; g4 < 4; g4++) {
            int d = dt * 32 + g4 * 8 + lhi * 4;  // regs 4*g4.. -> d..d+3
            float4 pv = *(const float4*)(pos + rowbase + d);
            uint2 o;
            o.x = cvt2bf(oacc[dt][g4 * 4 + 0] * inv + pv.x, oacc[dt][g4 * 4 + 1] * inv + pv.y);
            o.y = cvt2bf(oacc[dt][g4 * 4 + 2] * inv + pv.z, oacc[dt][g4 * 4 + 3] * inv + pv.w);
            *(uint2*)(att + rowbase + d) = o;
        }
}

extern "C" void kernel_launch(void* const* d_in, const int* in_sizes, int n_in,
                              void* d_out, int out_size, void* d_ws, size_t ws_size,
                              hipStream_t stream) {
    const float* x = (const float*)d_in[0];
    const float* pos = (const float*)d_in[1];
    const float* w_qkv = (const float*)d_in[2];
    const float* w_out = (const float*)d_in[3];
    const float* b_out = (const float*)d_in[4];
    const float* ln_g = (const float*)d_in[5];
    const float* ln_b = (const float*)d_in[6];
    float* out = (float*)d_out;

    char* ws = (char*)d_ws;
    unsigned short* xn      = (unsigned short*)(ws);                       // 16MB (reused as att)
    unsigned short* wqkv_bt = (unsigned short*)(ws + (16ull << 20));       // 6MB
    unsigned short* wout_bt = (unsigned short*)(ws + (22ull << 20));       // 2MB
    unsigned short* Qb      = (unsigned short*)(ws + (24ull << 20));       // 16MB
    unsigned short* Kb      = (unsigned short*)(ws + (40ull << 20));       // 16MB
    unsigned short* Vt      = (unsigned short*)(ws + (56ull << 20));       // 16MB
    unsigned short* att     = xn;                                          // reuse

    transpose_to_bf16<<<dim3(N3 / 64, DIM / 64), 256, 0, stream>>>(w_qkv, wqkv_bt, DIM, N3);
    transpose_to_bf16<<<dim3(DIM / 64, DIM / 64), 256, 0, stream>>>(w_out, wout_bt, DIM, DIM);
    ln_kernel<<<TOKENS, 256, 0, stream>>>(x, ln_g, ln_b, xn);
    gemm_qkv<<<dim3(N3 / 128, TOKENS / 128), 256, 0, stream>>>(xn, wqkv_bt, Qb, Kb, Vt);
    attn_kernel<<<dim3(16, 64), 256, 0, stream>>>(Qb, Kb, Vt, pos, att);
    gemm_out<<<dim3(DIM / 128, TOKENS / 128), 256, 0, stream>>>(att, wout_bt, b_out, out);
}

// Round 5
// 220.735 us; speedup vs baseline: 1.2750x; 1.2750x over previous
//
#include <hip/hip_runtime.h>
#include <math.h>
#include <stdint.h>

#define TOKENS 8192
#define DIM 1024
#define N3 3072
#define NSEQ 2048
#define NH 16
#define DH 64

typedef __attribute__((ext_vector_type(8))) __bf16 bf16x8;
typedef __attribute__((ext_vector_type(4))) float f32x4;
typedef __attribute__((ext_vector_type(16))) float f32x16;
typedef __attribute__((ext_vector_type(4))) short short4v;

// hardware bf16 convert (RNE) — no builtin on gfx950, inline asm per T12/m240
__device__ __forceinline__ unsigned cvt2bf(float a, float b) {
    unsigned r;
    asm("v_cvt_pk_bf16_f32 %0, %1, %2" : "=v"(r) : "v"(a), "v"(b));
    return r;
}
__device__ __forceinline__ unsigned short f2bf(float f) {
    unsigned r;
    asm("v_cvt_pk_bf16_f32 %0, %1, %1" : "=v"(r) : "v"(f));
    return (unsigned short)r;
}
// raw v_exp_f32 (2^x); safe for finite x (we never pass +inf; -inf -> 0)
__device__ __forceinline__ float exp2_raw(float x) {
    float r;
    asm("v_exp_f32 %0, %1" : "=v"(r) : "v"(x));
    return r;
}

__device__ __forceinline__ void glds16(const void* g, void* l) {
    __builtin_amdgcn_global_load_lds((__attribute__((address_space(1))) void*)(void*)g,
                                     (__attribute__((address_space(3))) void*)l, 16, 0, 0);
}

// ---------------- transpose f32 [R][C] -> bf16 [C][R] ----------------
__global__ __launch_bounds__(256) void transpose_to_bf16(
    const float* __restrict__ in, unsigned short* __restrict__ out, int R, int C) {
    __shared__ float tile[64][65];
    int n0 = blockIdx.x * 64, k0 = blockIdx.y * 64;
    int t = threadIdx.x;
#pragma unroll
    for (int i = 0; i < 16; i++) {
        int idx = i * 256 + t;
        int r = idx >> 6, c = idx & 63;
        tile[r][c] = in[(size_t)(k0 + r) * C + n0 + c];
    }
    __syncthreads();
#pragma unroll
    for (int i = 0; i < 16; i++) {
        int idx = i * 256 + t;
        int r = idx >> 6, c = idx & 63;
        out[(size_t)(n0 + r) * R + k0 + c] = f2bf(tile[c][r]);
    }
}

// ---------------- LayerNorm: f32 [8192][1024] -> bf16 ----------------
__global__ __launch_bounds__(256) void ln_kernel(
    const float* __restrict__ x, const float* __restrict__ gamma,
    const float* __restrict__ beta, unsigned short* __restrict__ xn) {
    int row = blockIdx.x;
    int t = threadIdx.x;
    const float4 v = ((const float4*)(x + (size_t)row * DIM))[t];
    float s = v.x + v.y + v.z + v.w;
    float sq = v.x * v.x + v.y * v.y + v.z * v.z + v.w * v.w;
#pragma unroll
    for (int m = 1; m < 64; m <<= 1) {
        s += __shfl_xor(s, m);
        sq += __shfl_xor(sq, m);
    }
    __shared__ float ws[4], wq[4];
    int w = t >> 6, lane = t & 63;
    if (lane == 0) { ws[w] = s; wq[w] = sq; }
    __syncthreads();
    s = ws[0] + ws[1] + ws[2] + ws[3];
    sq = wq[0] + wq[1] + wq[2] + wq[3];
    float mu = s * (1.0f / DIM);
    float var = sq * (1.0f / DIM) - mu * mu;
    float rstd = rsqrtf(var + 1e-5f);
    const float4 g = ((const float4*)gamma)[t];
    const float4 bb = ((const float4*)beta)[t];
    uint2 o;
    o.x = cvt2bf((v.x - mu) * rstd * g.x + bb.x, (v.y - mu) * rstd * g.y + bb.y);
    o.y = cvt2bf((v.z - mu) * rstd * g.z + bb.z, (v.w - mu) * rstd * g.w + bb.w);
    *(uint2*)(xn + (size_t)row * DIM + t * 4) = o;
}

// XCD-aware bijective swizzle of the linear workgroup id (nwg % 8 == 0)
__device__ __forceinline__ void xcd_swizzle(int& bx, int& by) {
    int nwgx = gridDim.x;
    int nwg = nwgx * gridDim.y;
    int wg = by * nwgx + bx;
    int cpx = nwg >> 3;
    int swz = (wg & 7) * cpx + (wg >> 3);
    bx = swz % nwgx;
    by = swz / nwgx;
}

// ---------------- shared GEMM core: C[128x128] = A[M,K] * Bt[N,K]^T ----------------
__device__ __forceinline__ void gemm_core(
    const unsigned short* __restrict__ A, const unsigned short* __restrict__ Bt, int K,
    int brow, int bcol, short* As, short* Bs, f32x4 acc[4][4]) {
    int t = threadIdx.x, w = t >> 6, lane = t & 63;
    int wr = w >> 1, wc = w & 1;
    int srow = lane >> 2, scol = (lane & 3) * 8;
    for (int k0 = 0; k0 < K; k0 += 32) {
        __syncthreads();
#pragma unroll
        for (int i = 0; i < 2; i++) {
            int c = i * 4 + w;
            glds16(A + (size_t)(brow + 16 * c + srow) * K + k0 + scol, (char*)As + c * 1024);
            glds16(Bt + (size_t)(bcol + 16 * c + srow) * K + k0 + scol, (char*)Bs + c * 1024);
        }
        __syncthreads();
        bf16x8 a[4], b[4];
#pragma unroll
        for (int i = 0; i < 4; i++) {
            a[i] = *(const bf16x8*)&As[(wr * 64 + i * 16 + (lane & 15)) * 32 + (lane >> 4) * 8];
            b[i] = *(const bf16x8*)&Bs[(wc * 64 + i * 16 + (lane & 15)) * 32 + (lane >> 4) * 8];
        }
#pragma unroll
        for (int i = 0; i < 4; i++)
#pragma unroll
            for (int j = 0; j < 4; j++)
                acc[i][j] = __builtin_amdgcn_mfma_f32_16x16x32_bf16(a[i], b[j], acc[i][j], 0, 0, 0);
    }
}

// QKV GEMM: xn[8192][1024] @ w_qkv -> writes Q (scaled), K, V^T in [b,h,...] layouts
#define QSCALE_LOG2E 0.18033688011112042f  // (1/sqrt(64)) * log2(e)

__global__ __launch_bounds__(256) void gemm_qkv(
    const unsigned short* __restrict__ A, const unsigned short* __restrict__ Bt,
    unsigned short* __restrict__ Qb, unsigned short* __restrict__ Kb,
    unsigned short* __restrict__ Vt) {
    __shared__ __align__(16) short As[128 * 32];
    __shared__ __align__(16) short Bs[128 * 32];
    int bx = blockIdx.x, by = blockIdx.y;
    xcd_swizzle(bx, by);
    int brow = by * 128, bcol = bx * 128;
    f32x4 acc[4][4] = {};
    gemm_core(A, Bt, DIM, brow, bcol, As, Bs, acc);

    int t = threadIdx.x, w = t >> 6, lane = t & 63;
    int wr = w >> 1, wc = w & 1;
    int part = bcol >> 10;  // uniform per block: 0=q 1=k 2=v
#pragma unroll
    for (int i = 0; i < 4; i++) {
#pragma unroll
        for (int j = 0; j < 4; j++) {
            int col = bcol + wc * 64 + j * 16 + (lane & 15);
            int within = col & 1023;
            int h = within >> 6, d = within & 63;
            int rowb = brow + wr * 64 + i * 16 + (lane >> 4) * 4;
            if (part == 2) {
                // V^T: n consecutive over r -> pack 4
                int b = rowb >> 11, n = rowb & 2047;
                int bh = (b << 4) + h;
                uint2 pv;
                pv.x = cvt2bf(acc[i][j][0], acc[i][j][1]);
                pv.y = cvt2bf(acc[i][j][2], acc[i][j][3]);
                *(uint2*)(Vt + ((size_t)bh * 64 + d) * 2048 + n) = pv;
            } else {
#pragma unroll
                for (int r = 0; r < 4; r++) {
                    int row = rowb + r;
                    int b = row >> 11, n = row & 2047;
                    int bh = (b << 4) + h;
                    float val = acc[i][j][r];
                    if (part == 0)
                        Qb[((size_t)bh * 2048 + n) * 64 + d] = f2bf(val * QSCALE_LOG2E);
                    else
                        Kb[((size_t)bh * 2048 + n) * 64 + d] = f2bf(val);
                }
            }
        }
    }
}

// out GEMM: att[8192][1024] @ w_out + b_out -> f32 out
__global__ __launch_bounds__(256) void gemm_out(
    const unsigned short* __restrict__ A, const unsigned short* __restrict__ Bt,
    const float* __restrict__ bias, float* __restrict__ out) {
    __shared__ __align__(16) short As[128 * 32];
    __shared__ __align__(16) short Bs[128 * 32];
    int bx = blockIdx.x, by = blockIdx.y;
    xcd_swizzle(bx, by);
    int brow = by * 128, bcol = bx * 128;
    f32x4 acc[4][4] = {};
    gemm_core(A, Bt, DIM, brow, bcol, As, Bs, acc);

    int t = threadIdx.x, w = t >> 6, lane = t & 63;
    int wr = w >> 1, wc = w & 1;
#pragma unroll
    for (int i = 0; i < 4; i++) {
#pragma unroll
        for (int j = 0; j < 4; j++) {
            int col = bcol + wc * 64 + j * 16 + (lane & 15);
            float bv = bias[col];
#pragma unroll
            for (int r = 0; r < 4; r++) {
                int row = brow + wr * 64 + i * 16 + (lane >> 4) * 4 + r;
                out[(size_t)row * DIM + col] = acc[i][j][r] + bv;
            }
        }
    }
}

// ---------------- flash attention v3: counted-vmcnt pipeline (T3/T4) ----------------
// grid (8, 64) x 512 threads: 8 waves/block, QBLK=32 rows/wave (block = 256 q-rows).
// 3-buffer LDS, 2-deep prefetch: per tile {wait vmcnt(2); s_barrier; stage(t+2); compute(t)}.
// Never vmcnt(0) in the loop; raw s_barrier (no compiler drain). In-register softmax,
// raw v_exp_f32, balanced max tree + 4-way partial sums.
#define LOG2E_THR 11.5f  // defer-max threshold: 8 * log2(e)

__global__ __launch_bounds__(512, 4) void attn_kernel(
    const unsigned short* __restrict__ Qb, const unsigned short* __restrict__ Kb,
    const unsigned short* __restrict__ Vt, const float* __restrict__ pos,
    unsigned short* __restrict__ att) {
    __shared__ __align__(16) char Ks[3][8192];
    __shared__ __align__(16) char Vs[3][8192];
    int t = threadIdx.x, w = t >> 6, lane = t & 63;
    int l31 = lane & 31, lhi = lane >> 5;

    // XCD head-grouping: all q-tiles of head-batch bh land on XCD bh%8
    int L = blockIdx.y * gridDim.x + blockIdx.x;      // 0..511
    int bh = (L & 7) + (((L >> 3) & 7) << 3);         // head-batch index 0..63
    int qt = L >> 6;                                  // q-tile 0..7
    int b = bh >> 4, h = bh & 15;
    int qr = qt * 256 + w * 32 + l31;                 // this lane's q row

    const unsigned short* Qh = Qb + (size_t)bh * NSEQ * DH;
    const char* Khc = (const char*)(Kb + (size_t)bh * NSEQ * DH);
    const char* Vhc = (const char*)(Vt + (size_t)bh * DH * NSEQ);

    // Q fragments: qf[ks] = Q[qr][ks*16 + lhi*8 .. +8]
    bf16x8 qf[4];
#pragma unroll
    for (int ks = 0; ks < 4; ks++)
        qf[ks] = *(const bf16x8*)(Qh + (size_t)qr * DH + ks * 16 + lhi * 8);

    f32x16 oacc[2] = {};
    float mrun = -INFINITY, lsum = 0.f;  // per-lane partials (pair-combined at epilogue)

    // fragment-ordered cooperative stage: wave w supplies chunk c=w (1 K + 1 V load)
    int ct = w >> 2, cs = w & 3;
    const char* Ksrc = Khc + (size_t)(ct * 32 + l31) * 128 + cs * 32 + lhi * 16;
    const char* Vsrc = Vhc + (size_t)(ct * 32 + l31) * 4096 + (size_t)(cs * 16 + lhi * 8) * 2;
    auto stage = [&](char* kbuf, char* vbuf, int kv0) {
        glds16(Ksrc + (size_t)kv0 * 128, kbuf + w * 1024);
        glds16(Vsrc + (size_t)kv0 * 2, vbuf + w * 1024);
    };

    char* k0 = Ks[0]; char* k1 = Ks[1]; char* k2 = Ks[2];
    char* v0 = Vs[0]; char* v1 = Vs[1]; char* v2 = Vs[2];
    stage(k0, v0, 0);
    stage(k1, v1, 64);

    for (int tl = 0; tl < 32; ++tl) {
        asm volatile("s_waitcnt vmcnt(2)" ::: "memory");  // tile tl's loads done (per-wave)
        __builtin_amdgcn_s_barrier();                     // all waves' loads done; buf k2 free
        stage(k2, v2, ((tl + 2) & 31) << 6);              // prefetch tile tl+2 (wraps, harmless)

        // QK^T: st[kt] = S^T tile; lane = q-col (l31), rows m(r)+4*lhi, kv=tl*64+kt*32+...
        f32x16 st[2];
        __builtin_amdgcn_s_setprio(1);
#pragma unroll
        for (int kt = 0; kt < 2; kt++) {
            f32x16 s = {};
#pragma unroll
            for (int ks = 0; ks < 4; ks++) {
                bf16x8 kf = *(const bf16x8*)(k0 + (kt * 4 + ks) * 1024 + lane * 16);
                s = __builtin_amdgcn_mfma_f32_32x32x16_bf16(kf, qf[ks], s, 0, 0, 0);
            }
            st[kt] = s;
        }
        __builtin_amdgcn_s_setprio(0);

        // balanced max tree over 32 vals, then pair-combine via permlane32_swap
        float mx[8];
#pragma unroll
        for (int r = 0; r < 8; r++)
            mx[r] = fmaxf(fmaxf(st[0][r], st[0][r + 8]), fmaxf(st[1][r], st[1][r + 8]));
#pragma unroll
        for (int sft = 4; sft >= 1; sft >>= 1)
#pragma unroll
            for (int r = 0; r < sft; r++) mx[r] = fmaxf(mx[r], mx[r + sft]);
        float pm = mx[0];
        {
            float pa = pm, pb = pm;
            asm("v_permlane32_swap_b32 %0, %1" : "+v"(pa), "+v"(pb));
            pm = fmaxf(pa, pb);
        }
        if (!__all(pm - mrun <= LOG2E_THR)) {
            float mnew = fmaxf(mrun, pm);
            float scale = exp2_raw(mrun - mnew);
            lsum *= scale;
            oacc[0] *= scale;
            oacc[1] *= scale;
            mrun = mnew;
        }
        // P = exp2(S - mrun) in place; 4-way partial row-sum (per-lane)
        float r4[4] = {0.f, 0.f, 0.f, 0.f};
#pragma unroll
        for (int kt = 0; kt < 2; kt++)
#pragma unroll
            for (int r = 0; r < 16; r++) {
                float e = exp2_raw(st[kt][r] - mrun);
                st[kt][r] = e;
                r4[r & 3] += e;
            }
        lsum += (r4[0] + r4[1]) + (r4[2] + r4[3]);

        // build PV B-frags in-register: cvt_pk pairs + permlane32_swap (T12)
        bf16x8 bfr[4];
#pragma unroll
        for (int ks = 0; ks < 4; ks++) {
            int kt = ks >> 1, rb = (ks & 1) * 8;
            unsigned pa = cvt2bf(st[kt][rb + 0], st[kt][rb + 1]);
            unsigned pc = cvt2bf(st[kt][rb + 2], st[kt][rb + 3]);
            unsigned pb = cvt2bf(st[kt][rb + 4], st[kt][rb + 5]);
            unsigned pd = cvt2bf(st[kt][rb + 6], st[kt][rb + 7]);
            asm("v_permlane32_swap_b32 %0, %1" : "+v"(pa), "+v"(pb));
            asm("v_permlane32_swap_b32 %0, %1" : "+v"(pc), "+v"(pd));
            uint4 pw = {pa, pc, pb, pd};
            bfr[ks] = *(bf16x8*)&pw;
        }

        // PV: oacc[dt] += V^T_frag(dt,ks) * P^T_frag(ks)
        __builtin_amdgcn_s_setprio(1);
#pragma unroll
        for (int ks = 0; ks < 4; ks++)
#pragma unroll
            for (int dt = 0; dt < 2; dt++) {
                bf16x8 vf = *(const bf16x8*)(v0 + (dt * 4 + ks) * 1024 + lane * 16);
                oacc[dt] = __builtin_amdgcn_mfma_f32_32x32x16_bf16(vf, bfr[ks], oacc[dt], 0, 0, 0);
            }
        __builtin_amdgcn_s_setprio(0);

        // rotate buffers: k0<-k1<-k2<-k0
        char* tk = k0; k0 = k1; k1 = k2; k2 = tk;
        char* tv = v0; v0 = v1; v1 = v2; v2 = tv;
    }

    // epilogue: pair-combine lsum, then out[q][d] = oacc/lsum + pos, bf16
    {
        float pa = lsum, pb = lsum;
        asm("v_permlane32_swap_b32 %0, %1" : "+v"(pa), "+v"(pb));
        lsum = pa + pb;
    }
    float inv = 1.0f / lsum;
    size_t rowbase = ((size_t)b * NSEQ + qr) * DIM + h * 64;
#pragma unroll
    for (int dt = 0; dt < 2; dt++)
#pragma unroll
        for (int g4 = 0; g4 < 4; g4++) {
            int d = dt * 32 + g4 * 8 + lhi * 4;
            float4 pv = *(const float4*)(pos + rowbase + d);
            uint2 o;
            o.x = cvt2bf(oacc[dt][g4 * 4 + 0] * inv + pv.x, oacc[dt][g4 * 4 + 1] * inv + pv.y);
            o.y = cvt2bf(oacc[dt][g4 * 4 + 2] * inv + pv.z, oacc[dt][g4 * 4 + 3] * inv + pv.w);
            *(uint2*)(att + rowbase + d) = o;
        }
}

extern "C" void kernel_launch(void* const* d_in, const int* in_sizes, int n_in,
                              void* d_out, int out_size, void* d_ws, size_t ws_size,
                              hipStream_t stream) {
    const float* x = (const float*)d_in[0];
    const float* pos = (const float*)d_in[1];
    const float* w_qkv = (const float*)d_in[2];
    const float* w_out = (const float*)d_in[3];
    const float* b_out = (const float*)d_in[4];
    const float* ln_g = (const float*)d_in[5];
    const float* ln_b = (const float*)d_in[6];
    float* out = (float*)d_out;

    char* ws = (char*)d_ws;
    unsigned short* xn      = (unsigned short*)(ws);                       // 16MB (reused as att)
    unsigned short* wqkv_bt = (unsigned short*)(ws + (16ull << 20));       // 6MB
    unsigned short* wout_bt = (unsigned short*)(ws + (22ull << 20));       // 2MB
    unsigned short* Qb      = (unsigned short*)(ws + (24ull << 20));       // 16MB
    unsigned short* Kb      = (unsigned short*)(ws + (40ull << 20));       // 16MB
    unsigned short* Vt      = (unsigned short*)(ws + (56ull << 20));       // 16MB
    unsigned short* att     = xn;                                          // reuse

    transpose_to_bf16<<<dim3(N3 / 64, DIM / 64), 256, 0, stream>>>(w_qkv, wqkv_bt, DIM, N3);
    transpose_to_bf16<<<dim3(DIM / 64, DIM / 64), 256, 0, stream>>>(w_out, wout_bt, DIM, DIM);
    ln_kernel<<<TOKENS, 256, 0, stream>>>(x, ln_g, ln_b, xn);
    gemm_qkv<<<dim3(N3 / 128, TOKENS / 128), 256, 0, stream>>>(xn, wqkv_bt, Qb, Kb, Vt);
    attn_kernel<<<dim3(NSEQ / 256, 64), 512, 0, stream>>>(Qb, Kb, Vt, pos, att);
    gemm_out<<<dim3(DIM / 128, TOKENS / 128), 256, 0, stream>>>(att, wout_bt, b_out, out);
}